// Round 11
// baseline (85.889 us; speedup 1.0000x reference)
//
#include <hip/hip_runtime.h>
#include <hip/hip_bf16.h>

constexpr int KST  = 12;
constexpr int NN   = 10;
constexpr int B    = 2;
constexpr int C    = 512;
constexpr int T    = 4096;
constexpr int BAND = 12;
constexpr int NCH  = C / 32;   // 16 k-chunks of 32

typedef float f32x4  __attribute__((ext_vector_type(4)));
typedef short bf16x8 __attribute__((ext_vector_type(8)));
typedef unsigned short u16x8 __attribute__((ext_vector_type(8)));

__device__ __forceinline__ float logsig(float x) {
    return fminf(x, 0.0f) - log1pf(expf(-fabsf(x)));
}
__device__ __forceinline__ unsigned short f2bf(float f) {
    union { float f; unsigned u; } v; v.f = f;
    unsigned r = v.u + 0x7fff + ((v.u >> 16) & 1);   // RNE
    return (unsigned short)(r >> 16);
}
__device__ __forceinline__ float bf2f(unsigned short h) {
    union { unsigned u; float f; } v; v.u = (unsigned)h << 16;
    return v.f;
}

// ---------------------------------------------------------------------------
// prep:
//  [0, 1024)    : transpose-PACK fc[b][c][t] fp32 -> fcp[b][c/32][t][c%32] bf16
//  [1024, 1280) : pack W[d][k] -> Wp[k/32][d][k%32] bf16 ; zero out[0]
// (enc is NOT transposed: the band kernel streams it natively.)
// ---------------------------------------------------------------------------
constexpr int PREP_TRANS_END = 1024;
constexpr int PREP_GRID      = PREP_TRANS_END + (C * C) / (256 * 4);  // 1280

__global__ __launch_bounds__(256) void prep(
    const float* __restrict__ fc, const float* __restrict__ W,
    unsigned short* __restrict__ fcp, unsigned short* __restrict__ Wp,
    float* __restrict__ out)
{
    __shared__ float lt[64][65];   // [t][c], pad -> 2-way banks (free)
    const int bid = blockIdx.x;
    const int tid = threadIdx.x;

    if (bid < PREP_TRANS_END) {
        const int b   = bid >> 9;
        const int rem = bid & 511;
        const int t0  = (rem & 63) * 64;
        const int c0  = (rem >> 6) * 64;
        const float* src = fc + (size_t)b * C * T;
        unsigned short* dst = fcp + (size_t)b * NCH * T * 32;

        const int tq = (tid & 15) * 4;
        const int cr = tid >> 4;           // 0..15
        #pragma unroll
        for (int p = 0; p < 4; ++p) {
            const int c_row = p * 16 + cr;
            const float4 v = *(const float4*)&src[(size_t)(c0 + c_row) * T + t0 + tq];
            lt[tq + 0][c_row] = v.x;
            lt[tq + 1][c_row] = v.y;
            lt[tq + 2][c_row] = v.z;
            lt[tq + 3][c_row] = v.w;
        }
        __syncthreads();

        const int t_row = tid >> 2;
        const int cq    = (tid & 3) * 16;
        u16x8 o0, o1;
        #pragma unroll
        for (int u = 0; u < 8; ++u) o0[u] = f2bf(lt[t_row][cq + u]);
        #pragma unroll
        for (int u = 0; u < 8; ++u) o1[u] = f2bf(lt[t_row][cq + 8 + u]);
        const int cg = c0 + cq;            // global c (mult of 16)
        const int ks = cg >> 5;
        const int j0 = cg & 31;            // 0 or 16
        unsigned short* dp = dst + ((size_t)ks * T + t0 + t_row) * 32 + j0;
        *(u16x8*)dp       = o0;
        *(u16x8*)(dp + 8) = o1;
    } else {
        if (bid == PREP_TRANS_END && tid == 0) out[0] = 0.0f;
        const int idx = ((bid - PREP_TRANS_END) * 256 + tid) * 4;
        const int d = idx >> 9;
        const int k = idx & 511;
        const float4 v = *(const float4*)&W[idx];
        ushort4 o;
        o.x = f2bf(v.x); o.y = f2bf(v.y); o.z = f2bf(v.z); o.w = f2bf(v.w);
        *(ushort4*)&Wp[((size_t)(k >> 5) * C + d) * 32 + (k & 31)] = o;
    }
}

// ---------------------------------------------------------------------------
// cgemm: c[b][d][t] = sum_k W[d][k]*fc[k][t] + bias[d]  (bf16 out, NATIVE
// [d][t] layout). Block 64d x 64t, 256 thr = 4 waves (2x2), wave 32d x 32t.
// Grid (T/64, C/64, B) = 1024 blocks -> 4 blocks/CU.
// Operands: packed fragment-major (1KB contiguous per fragment).
// Epilogue: frags -> padded LDS [64][68] -> coalesced 16B-per-lane stores.
// ---------------------------------------------------------------------------
__global__ __launch_bounds__(256) void cgemm(
    const unsigned short* __restrict__ Wp, const unsigned short* __restrict__ fcp,
    const float* __restrict__ bias, unsigned short* __restrict__ cb)
{
    const int b  = blockIdx.z;
    const int t0 = blockIdx.x * 64;
    const int d0 = blockIdx.y * 64;

    __shared__ unsigned short c_lds[64][68];   // +4 pad: conflict-free frag writes

    const int lane = threadIdx.x & 63;
    const int w    = threadIdx.x >> 6;
    const int wd   = (w & 1) * 32;
    const int wt   = (w >> 1) * 32;
    const int l15  = lane & 15;
    const int l4   = lane >> 4;

    const unsigned short* fcpb = fcp + (size_t)b * NCH * T * 32;
    const unsigned short* An  = Wp   + (size_t)(d0 + wd + l15) * 32 + l4 * 8;
    const unsigned short* Bn  = fcpb + (size_t)(t0 + wt + l15) * 32 + l4 * 8;

    f32x4 acc[2][2] = {};
    #pragma unroll 4
    for (int ks = 0; ks < NCH; ++ks) {
        const size_t ao = (size_t)ks * C * 32;
        const size_t bo = (size_t)ks * T * 32;
        const bf16x8 a0 = *(const bf16x8*)(An + ao);
        const bf16x8 a1 = *(const bf16x8*)(An + ao + 16 * 32);
        const bf16x8 b0 = *(const bf16x8*)(Bn + bo);
        const bf16x8 b1 = *(const bf16x8*)(Bn + bo + 16 * 32);
        acc[0][0] = __builtin_amdgcn_mfma_f32_16x16x32_bf16(a0, b0, acc[0][0], 0, 0, 0);
        acc[0][1] = __builtin_amdgcn_mfma_f32_16x16x32_bf16(a0, b1, acc[0][1], 0, 0, 0);
        acc[1][0] = __builtin_amdgcn_mfma_f32_16x16x32_bf16(a1, b0, acc[1][0], 0, 0, 0);
        acc[1][1] = __builtin_amdgcn_mfma_f32_16x16x32_bf16(a1, b1, acc[1][1], 0, 0, 0);
    }

    #pragma unroll
    for (int i = 0; i < 2; ++i) {
        const int drow = wd + i * 16 + l4 * 4;             // local d (mult of 4)
        const float4 bv = *(const float4*)&bias[d0 + drow];
        const float bvr[4] = {bv.x, bv.y, bv.z, bv.w};
        #pragma unroll
        for (int j = 0; j < 2; ++j) {
            const int col = wt + j * 16 + l15;
            #pragma unroll
            for (int r = 0; r < 4; ++r)
                c_lds[drow + r][col] = f2bf(acc[i][j][r] + bvr[r]);
        }
    }
    __syncthreads();

    const int row = threadIdx.x >> 2;
    const int cq  = (threadIdx.x & 3) * 16;
    const u16x8 o0 = *(const u16x8*)&c_lds[row][cq];
    const u16x8 o1 = *(const u16x8*)&c_lds[row][cq + 8];
    unsigned short* dp = cb + (size_t)b * C * T + (size_t)(d0 + row) * T + t0 + cq;
    *(u16x8*)dp       = o0;
    *(u16x8*)(dp + 8) = o1;
}

// ---------------------------------------------------------------------------
// band: streaming VALU contraction over d (no transpose, no MFMA).
//   diag_k[s] = sum_d enc[d][s+k]*c[d][s]  (k=0..11) -> logsig -> atomicAdd
//   neg_n[s]  = sum_d enc[d][n]  *c[d][s]  (n=0..9)  -> negls = logsig(-v)
// Block: 256 thr = 8 s-lanes x 32 d-groups(16 d each). Grid (T/8, B) = 1024.
// ---------------------------------------------------------------------------
__global__ __launch_bounds__(256) void band_kernel(
    const float* __restrict__ enc, const unsigned short* __restrict__ cb,
    float* __restrict__ negls, float* __restrict__ out)
{
    const int b   = blockIdx.y;
    const int s0  = blockIdx.x * 8;
    const int tid = threadIdx.x;
    const int sl  = tid & 7;
    const int g   = tid >> 3;          // 0..31
    const int s   = s0 + sl;

    const float* encb = enc + (size_t)b * C * T;
    const unsigned short* cbb = cb + (size_t)b * C * T;

    float acc[22];
    #pragma unroll
    for (int a = 0; a < 22; ++a) acc[a] = 0.0f;

    #pragma unroll 4
    for (int dd = 0; dd < 16; ++dd) {
        const int d = g * 16 + dd;
        const float* er = encb + (size_t)d * T;
        const float cc = bf2f(cbb[(size_t)d * T + s]);
        #pragma unroll
        for (int k = 0; k < BAND; ++k) {
            int t = s + k; t = t < T ? t : T - 1;   // clamp; masked at reduce
            acc[k] += er[t] * cc;
        }
        const float4 e0 = *(const float4*)&er[0];
        const float4 e1 = *(const float4*)&er[4];
        const float2 e2 = *(const float2*)&er[8];
        acc[12] += e0.x * cc; acc[13] += e0.y * cc;
        acc[14] += e0.z * cc; acc[15] += e0.w * cc;
        acc[16] += e1.x * cc; acc[17] += e1.y * cc;
        acc[18] += e1.z * cc; acc[19] += e1.w * cc;
        acc[20] += e2.x * cc; acc[21] += e2.y * cc;
    }

    __shared__ float red[32][22][9];   // pad 9 -> low-order bank spread
    #pragma unroll
    for (int a = 0; a < 22; ++a) red[g][a][sl] = acc[a];
    __syncthreads();

    float pos = 0.0f;
    if (tid < 176) {
        const int a   = tid >> 3;
        const int sl2 = tid & 7;
        const int s2  = s0 + sl2;
        float v = 0.0f;
        #pragma unroll
        for (int gg = 0; gg < 32; ++gg) v += red[gg][a][sl2];
        if (a < BAND) {
            if (s2 + a < T) pos = logsig(v);
        } else {
            negls[((size_t)b * NN + (a - BAND)) * T + s2] = logsig(-v);
        }
    }
    #pragma unroll
    for (int off = 32; off > 0; off >>= 1) pos += __shfl_down(pos, off, 64);
    __shared__ float wsum[4];
    if ((tid & 63) == 0) wsum[tid >> 6] = pos;
    __syncthreads();
    if (tid == 0) atomicAdd(out, wsum[0] + wsum[1] + wsum[2] + wsum[3]);
}

// ---------------------------------------------------------------------------
// gather: out += NN * sum logsig(-cont[b,n,idx]) via negls lookups.
// ---------------------------------------------------------------------------
__global__ __launch_bounds__(256) void gather_kernel(
    const int4* __restrict__ nidx4, const float* __restrict__ negls,
    float* __restrict__ out)
{
    const int i4 = blockIdx.x * 256 + threadIdx.x;
    const int4 vv = nidx4[i4];
    const int base = i4 * 4;
    const int idxs[4] = {vv.x, vv.y, vv.z, vv.w};
    float local = 0.0f;
    #pragma unroll
    for (int e = 0; e < 4; ++e) {
        const int n = (base + e) % NN;     // layout [k][t][n], n fastest
        local += negls[(size_t)n * T + idxs[e]]
               + negls[(size_t)(NN + n) * T + idxs[e]];
    }
    #pragma unroll
    for (int off = 32; off > 0; off >>= 1) local += __shfl_down(local, off, 64);
    __shared__ float wsum[4];
    if ((threadIdx.x & 63) == 0) wsum[threadIdx.x >> 6] = local;
    __syncthreads();
    if (threadIdx.x == 0)
        atomicAdd(out, (float)NN * (wsum[0] + wsum[1] + wsum[2] + wsum[3]));
}

// ---------------------------------------------------------------------------
extern "C" void kernel_launch(void* const* d_in, const int* in_sizes, int n_in,
                              void* d_out, int out_size, void* d_ws, size_t ws_size,
                              hipStream_t stream)
{
    const float* enc  = (const float*)d_in[0];
    const float* fc   = (const float*)d_in[1];
    const float* W    = (const float*)d_in[2];
    const float* bias = (const float*)d_in[3];
    const int4*  nidx4 = (const int4*)d_in[4];
    float* out = (float*)d_out;

    unsigned short* fcp = (unsigned short*)d_ws;                  // 8 MiB
    unsigned short* Wp  = fcp + (size_t)B * NCH * T * 32;         // 512 KiB
    unsigned short* cbuf = Wp + (size_t)C * C;                    // 8 MiB
    float* negls = (float*)(cbuf + (size_t)B * C * T);            // 320 KiB

    prep<<<PREP_GRID, 256, 0, stream>>>(fc, W, fcp, Wp, out);
    cgemm<<<dim3(T / 64, C / 64, B), 256, 0, stream>>>(Wp, fcp, bias, cbuf);
    band_kernel<<<dim3(T / 8, B), 256, 0, stream>>>(enc, cbuf, negls, out);
    gather_kernel<<<KST * T * NN / (4 * 256), 256, 0, stream>>>(
        nidx4, negls, out);
}

// Round 12
// 54.766 us; speedup vs baseline: 1.5683x; 1.5683x over previous
//
#include <hip/hip_runtime.h>
#include <hip/hip_bf16.h>

constexpr int KST  = 12;
constexpr int NN   = 10;
constexpr int B    = 2;
constexpr int C    = 512;
constexpr int T    = 4096;
constexpr int BAND = 12;
constexpr int NCH  = C / 32;   // 16 chunks of 32

typedef float f32x4  __attribute__((ext_vector_type(4)));
typedef short bf16x8 __attribute__((ext_vector_type(8)));
typedef unsigned short u16x8 __attribute__((ext_vector_type(8)));

__device__ __forceinline__ float logsig(float x) {
    return fminf(x, 0.0f) - log1pf(expf(-fabsf(x)));
}
__device__ __forceinline__ unsigned short f2bf(float f) {
    union { float f; unsigned u; } v; v.f = f;
    unsigned r = v.u + 0x7fff + ((v.u >> 16) & 1);   // RNE
    return (unsigned short)(r >> 16);
}

// ---------------------------------------------------------------------------
// prep_all:
//  [0, 2048)    : transpose-PACK X[b][c][t] fp32 -> Xp[b][c/32][t][c%32] bf16
//  [2048, 2304) : pack W[d][k] -> Wp[k/32][d][k%32] bf16 ; zero out[0]
// ---------------------------------------------------------------------------
constexpr int PREP_TRANS_END = 2048;
constexpr int PREP_GRID      = PREP_TRANS_END + (C * C) / (256 * 4);  // 2304

__global__ __launch_bounds__(256) void prep_all(
    const float* __restrict__ fc, const float* __restrict__ enc,
    const float* __restrict__ W,
    unsigned short* __restrict__ fcp, unsigned short* __restrict__ encp,
    unsigned short* __restrict__ Wp, float* __restrict__ out)
{
    __shared__ float lt[64][65];
    const int bid = blockIdx.x;
    const int tid = threadIdx.x;

    if (bid < PREP_TRANS_END) {
        const int z   = bid >> 9;
        const int rem = bid & 511;
        const int t0  = (rem & 63) * 64;
        const int c0  = (rem >> 6) * 64;
        const float* src = (z < 2 ? fc : enc) + (size_t)(z & 1) * C * T;
        unsigned short* dst =
            (z < 2 ? fcp : encp) + (size_t)(z & 1) * NCH * T * 32;

        const int tq = (tid & 15) * 4;
        const int cr = tid >> 4;
        #pragma unroll
        for (int p = 0; p < 4; ++p) {
            const int c_row = p * 16 + cr;
            const float4 v = *(const float4*)&src[(size_t)(c0 + c_row) * T + t0 + tq];
            lt[tq + 0][c_row] = v.x;
            lt[tq + 1][c_row] = v.y;
            lt[tq + 2][c_row] = v.z;
            lt[tq + 3][c_row] = v.w;
        }
        __syncthreads();

        const int t_row = tid >> 2;
        const int cq    = (tid & 3) * 16;
        u16x8 o0, o1;
        #pragma unroll
        for (int u = 0; u < 8; ++u) o0[u] = f2bf(lt[t_row][cq + u]);
        #pragma unroll
        for (int u = 0; u < 8; ++u) o1[u] = f2bf(lt[t_row][cq + 8 + u]);
        const int cg = c0 + cq;
        const int ks = cg >> 5;
        const int j0 = cg & 31;
        unsigned short* dp = dst + ((size_t)ks * T + t0 + t_row) * 32 + j0;
        *(u16x8*)dp       = o0;
        *(u16x8*)(dp + 8) = o1;
    } else {
        if (bid == PREP_TRANS_END && tid == 0) out[0] = 0.0f;
        const int idx = ((bid - PREP_TRANS_END) * 256 + tid) * 4;
        const int d = idx >> 9;
        const int k = idx & 511;
        const float4 v = *(const float4*)&W[idx];
        ushort4 o;
        o.x = f2bf(v.x); o.y = f2bf(v.y); o.z = f2bf(v.z); o.w = f2bf(v.w);
        *(ushort4*)&Wp[((size_t)(k >> 5) * C + d) * 32 + (k & 31)] = o;
    }
}

// ---------------------------------------------------------------------------
// cgemm: cT[t][d] = sum_k fc^T[t][k] * W[d][k] + bias[d], output PACKED as
// cpk[b][d/32][t][d%32] bf16. Block 64t x 64d, 256 thr = 4 waves (2x2).
// Grid (T/64, C/64, B) = 1024 blocks -> 4 blocks/CU.
// A-frags (fcp rows=t) and B-frags (Wp rows=d) are contiguous 1KB wave-loads.
// Epilogue: frags -> padded LDS [64t][68d] -> packed 32B/thread stores.
// ---------------------------------------------------------------------------
__global__ __launch_bounds__(256) void cgemm(
    const unsigned short* __restrict__ Wp, const unsigned short* __restrict__ fcp,
    const float* __restrict__ bias, unsigned short* __restrict__ cpk)
{
    const int b  = blockIdx.z;
    const int t0 = blockIdx.x * 64;
    const int d0 = blockIdx.y * 64;

    __shared__ unsigned short c_lds[64][68];

    const int lane = threadIdx.x & 63;
    const int w    = threadIdx.x >> 6;
    const int wt   = (w >> 1) * 32;
    const int wd   = (w & 1) * 32;
    const int l15  = lane & 15;
    const int l4   = lane >> 4;

    const unsigned short* fcpb = fcp + (size_t)b * NCH * T * 32;
    const unsigned short* An = fcpb + (size_t)(t0 + wt + l15) * 32 + l4 * 8;
    const unsigned short* Bn = Wp   + (size_t)(d0 + wd + l15) * 32 + l4 * 8;

    f32x4 acc[2][2] = {};
    #pragma unroll 4
    for (int ks = 0; ks < NCH; ++ks) {
        const size_t ao = (size_t)ks * T * 32;
        const size_t bo = (size_t)ks * C * 32;
        const bf16x8 a0 = *(const bf16x8*)(An + ao);
        const bf16x8 a1 = *(const bf16x8*)(An + ao + 16 * 32);
        const bf16x8 b0 = *(const bf16x8*)(Bn + bo);
        const bf16x8 b1 = *(const bf16x8*)(Bn + bo + 16 * 32);
        acc[0][0] = __builtin_amdgcn_mfma_f32_16x16x32_bf16(a0, b0, acc[0][0], 0, 0, 0);
        acc[0][1] = __builtin_amdgcn_mfma_f32_16x16x32_bf16(a0, b1, acc[0][1], 0, 0, 0);
        acc[1][0] = __builtin_amdgcn_mfma_f32_16x16x32_bf16(a1, b0, acc[1][0], 0, 0, 0);
        acc[1][1] = __builtin_amdgcn_mfma_f32_16x16x32_bf16(a1, b1, acc[1][1], 0, 0, 0);
    }

    // D[row][col]: row = t-local (A), col = d-local (B)
    #pragma unroll
    for (int j = 0; j < 2; ++j) {
        const int dcol = wd + j * 16 + l15;
        const float bv = bias[d0 + dcol];
        #pragma unroll
        for (int i = 0; i < 2; ++i) {
            const int trow = wt + i * 16 + l4 * 4;
            #pragma unroll
            for (int r = 0; r < 4; ++r)
                c_lds[trow + r][dcol] = f2bf(acc[i][j][r] + bv);
        }
    }
    __syncthreads();

    // packed store: thread -> (t = tid>>2, piece = tid&3 of 16 ushorts)
    {
        const int t     = threadIdx.x >> 2;
        const int piece = threadIdx.x & 3;
        const int ks    = (d0 >> 5) + (piece >> 1);
        const int inner = (piece & 1) * 16;
        const u16x8 o0 = *(const u16x8*)&c_lds[t][piece * 16];
        const u16x8 o1 = *(const u16x8*)&c_lds[t][piece * 16 + 8];
        unsigned short* dp = cpk + (size_t)b * NCH * T * 32
                           + ((size_t)ks * T + t0 + t) * 32 + inner;
        *(u16x8*)dp       = o0;
        *(u16x8*)(dp + 8) = o1;
    }
}

// ---------------------------------------------------------------------------
// band: D[64 x 32] = enc-window rows x c cols, contract over d (16 chunks).
// Grid (T/32, B) = 256 blocks, 512 thr = 8 waves; wave (i2,j2) owns a
// 16x16 quadrant. Both operands packed: A = encp rows, B = cpk rows.
//   rows 0..43 : diagonals k=row-col in [0,12) -> logsig -> atomicAdd
//   rows 44..53: negls[b][n][scol] = logsig(-v)
// ---------------------------------------------------------------------------
__global__ __launch_bounds__(512) void band_kernel(
    const unsigned short* __restrict__ encp, const unsigned short* __restrict__ cpk,
    float* __restrict__ negls, float* __restrict__ out)
{
    const int b  = blockIdx.y;
    const int n0 = blockIdx.x * 32;
    __shared__ float posred[8];

    const int tid  = threadIdx.x;
    const int lane = tid & 63;
    const int w    = tid >> 6;
    const int l15  = lane & 15;
    const int l4   = lane >> 4;

    const unsigned short* encpb = encp + (size_t)b * NCH * T * 32;
    const unsigned short* cpkb  = cpk  + (size_t)b * NCH * T * 32;

    const int i2 = w >> 1;
    const int j2 = w & 1;
    const int rg = i2 * 16 + l15;
    int ti;
    if (rg < 44) { ti = n0 + rg; ti = ti < T ? ti : T - 1; }
    else if (rg < 54) ti = rg - 44;
    else ti = 0;
    const unsigned short* A2p = encpb + (size_t)ti * 32 + l4 * 8;
    const unsigned short* B2p = cpkb + (size_t)(n0 + j2 * 16 + l15) * 32 + l4 * 8;

    f32x4 dacc = {};
    #pragma unroll 4
    for (int ks = 0; ks < NCH; ++ks) {
        const size_t o = (size_t)ks * T * 32;
        const bf16x8 a2 = *(const bf16x8*)(A2p + o);
        const bf16x8 b2 = *(const bf16x8*)(B2p + o);
        dacc = __builtin_amdgcn_mfma_f32_16x16x32_bf16(a2, b2, dacc, 0, 0, 0);
    }

    float pos = 0.0f;
    const int colr = j2 * 16 + l15;
    const int scol = n0 + colr;
    #pragma unroll
    for (int r = 0; r < 4; ++r) {
        const int row = i2 * 16 + l4 * 4 + r;
        const float vv = dacc[r];
        if (row < 44) {
            const int k = row - colr;
            if (k >= 0 && k < BAND && scol + k < T) pos += logsig(vv);
        } else if (row < 54) {
            negls[((size_t)b * NN + (row - 44)) * T + scol] = logsig(-vv);
        }
    }
    #pragma unroll
    for (int off = 32; off > 0; off >>= 1) pos += __shfl_down(pos, off, 64);
    if (lane == 0) posred[w] = pos;
    __syncthreads();
    if (tid == 0) {
        float tsum = 0.0f;
        #pragma unroll
        for (int q = 0; q < 8; ++q) tsum += posred[q];
        atomicAdd(out, tsum);
    }
}

// ---------------------------------------------------------------------------
// gather: out += NN * sum logsig(-cont[b,n,idx]) via negls lookups.
// ---------------------------------------------------------------------------
__global__ __launch_bounds__(256) void gather_kernel(
    const int4* __restrict__ nidx4, const float* __restrict__ negls,
    float* __restrict__ out)
{
    const int i4 = blockIdx.x * 256 + threadIdx.x;
    const int4 vv = nidx4[i4];
    const int base = i4 * 4;
    const int idxs[4] = {vv.x, vv.y, vv.z, vv.w};
    float local = 0.0f;
    #pragma unroll
    for (int e = 0; e < 4; ++e) {
        const int n = (base + e) % NN;
        local += negls[(size_t)n * T + idxs[e]]
               + negls[(size_t)(NN + n) * T + idxs[e]];
    }
    #pragma unroll
    for (int off = 32; off > 0; off >>= 1) local += __shfl_down(local, off, 64);
    __shared__ float wsum[4];
    if ((threadIdx.x & 63) == 0) wsum[threadIdx.x >> 6] = local;
    __syncthreads();
    if (threadIdx.x == 0)
        atomicAdd(out, (float)NN * (wsum[0] + wsum[1] + wsum[2] + wsum[3]));
}

// ---------------------------------------------------------------------------
extern "C" void kernel_launch(void* const* d_in, const int* in_sizes, int n_in,
                              void* d_out, int out_size, void* d_ws, size_t ws_size,
                              hipStream_t stream)
{
    const float* enc  = (const float*)d_in[0];
    const float* fc   = (const float*)d_in[1];
    const float* W    = (const float*)d_in[2];
    const float* bias = (const float*)d_in[3];
    const int4*  nidx4 = (const int4*)d_in[4];
    float* out = (float*)d_out;

    unsigned short* fcp  = (unsigned short*)d_ws;                 // 8 MiB
    unsigned short* encp = fcp  + (size_t)B * NCH * T * 32;       // 8 MiB
    unsigned short* Wp   = encp + (size_t)B * NCH * T * 32;       // 512 KiB
    unsigned short* cpk  = Wp   + (size_t)C * C;                  // 8 MiB
    float* negls = (float*)(cpk + (size_t)B * NCH * T * 32);      // 320 KiB

    prep_all<<<PREP_GRID, 256, 0, stream>>>(fc, enc, W, fcp, encp, Wp, out);
    cgemm<<<dim3(T / 64, C / 64, B), 256, 0, stream>>>(Wp, fcp, bias, cpk);
    band_kernel<<<dim3(T / 32, B), 512, 0, stream>>>(encp, cpk, negls, out);
    gather_kernel<<<KST * T * NN / (4 * 256), 256, 0, stream>>>(
        nidx4, negls, out);
}